// Round 1
// baseline (354.102 us; speedup 1.0000x reference)
//
#include <hip/hip_runtime.h>
#include <hip/hip_bf16.h>
#include <math.h>

// Problem constants (from reference): B=512, T=256, C=384, H=64
#define TT 256
#define CC 384
#define HH 64

typedef float v4f  __attribute__((ext_vector_type(4)));
typedef short short8 __attribute__((ext_vector_type(8)));

#define MFMA(a, b, c) __builtin_amdgcn_mfma_f32_16x16x32_bf16((a), (b), (c), 0, 0, 0)

__device__ __forceinline__ unsigned short f2bf(float f) {
    unsigned int u = __float_as_uint(f);
    u += 0x7FFFu + ((u >> 16) & 1u);   // round-to-nearest-even
    return (unsigned short)(u >> 16);
}

// LDS layout (ushort units):
//   q_s  [256][72]  : q rows, h-contiguous (stride 72 = 144B, mult of 16B, 2-way banks)
//   k_s  [256][72]  : k rows, h-contiguous
//   vt_s [64][264]  : v transposed, t-contiguous (stride 528B)
//   x_s  [256][40]  : phase-1 x K-tile (32 bf16 + pad); reused as P buffers in phase 2
//   w_s  [192][40]  : phase-1 W K-tile (rows: 0-63 Wq, 64-127 Wk, 128-191 Wv)
#define OFF_Q  0
#define OFF_K  18432
#define OFF_VT 36864
#define OFF_X  53760
#define OFF_W  64000
#define SMEM_BYTES (71680 * 2)

__global__ __launch_bounds__(512, 2)
void head_fused(const float* __restrict__ x, const float* __restrict__ Wkp,
                const float* __restrict__ Wqp, const float* __restrict__ Wvp,
                float* __restrict__ out)
{
    extern __shared__ unsigned short sm[];
    unsigned short* q_s  = sm + OFF_Q;
    unsigned short* k_s  = sm + OFF_K;
    unsigned short* vt_s = sm + OFF_VT;
    unsigned short* x_s  = sm + OFF_X;
    unsigned short* w_s  = sm + OFF_W;

    const int b    = blockIdx.x;
    const int tid  = threadIdx.x;
    const int wave = tid >> 6;
    const int lane = tid & 63;
    const int col  = lane & 15;   // MFMA n / m index
    const int quad = lane >> 4;   // MFMA k-chunk / row-group index

    const float* xb = x + (size_t)b * TT * CC;

    // ---------------- Phase 1: QKV projection (M=256, N=192, K=384) ----------------
    // Global-load mapping: 512 threads, each loads float4s.
    const int lrow = tid >> 3;        // 0..63
    const int lc4  = (tid & 7) * 4;   // float offset within 32-wide K-step

    const float* xp0 = xb  + lrow * CC + lc4;
    const float* wq0 = Wqp + lrow * CC + lc4;
    const float* wk0 = Wkp + lrow * CC + lc4;
    const float* wv0 = Wvp + lrow * CC + lc4;

    v4f acc[2][12];
    #pragma unroll
    for (int i = 0; i < 2; ++i)
        #pragma unroll
        for (int j = 0; j < 12; ++j)
            acc[i][j] = (v4f){0.f, 0.f, 0.f, 0.f};

    // prefetch step 0 into registers
    float4 xA[4]; float4 wA[3];
    #pragma unroll
    for (int i = 0; i < 4; ++i) xA[i] = *(const float4*)(xp0 + i * 64 * CC);
    wA[0] = *(const float4*)(wq0);
    wA[1] = *(const float4*)(wk0);
    wA[2] = *(const float4*)(wv0);

    const int mrow0 = ((wave * 2 + 0) * 16 + col) * 40 + quad * 8;
    const int mrow1 = ((wave * 2 + 1) * 16 + col) * 40 + quad * 8;

    #pragma unroll
    for (int s = 0; s < 12; ++s) {
        float4 xB[4]; float4 wB[3];
        if (s + 1 < 12) {   // issue next-step loads early: stay in flight across mfma
            const int k0 = (s + 1) * 32;
            #pragma unroll
            for (int i = 0; i < 4; ++i) xB[i] = *(const float4*)(xp0 + i * 64 * CC + k0);
            wB[0] = *(const float4*)(wq0 + k0);
            wB[1] = *(const float4*)(wk0 + k0);
            wB[2] = *(const float4*)(wv0 + k0);
        }
        __syncthreads();   // previous step's LDS reads complete
        #pragma unroll
        for (int i = 0; i < 4; ++i) {
            ushort4 u;
            u.x = f2bf(xA[i].x); u.y = f2bf(xA[i].y);
            u.z = f2bf(xA[i].z); u.w = f2bf(xA[i].w);
            *(ushort4*)&x_s[(i * 64 + lrow) * 40 + lc4] = u;
        }
        #pragma unroll
        for (int i = 0; i < 3; ++i) {
            ushort4 u;
            u.x = f2bf(wA[i].x); u.y = f2bf(wA[i].y);
            u.z = f2bf(wA[i].z); u.w = f2bf(wA[i].w);
            *(ushort4*)&w_s[(i * 64 + lrow) * 40 + lc4] = u;
        }
        __syncthreads();
        // A frags: one per m-tile (K-step == 32 == full MFMA K)
        short8 a0 = *(const short8*)&x_s[mrow0];
        short8 a1 = *(const short8*)&x_s[mrow1];
        #pragma unroll
        for (int nt = 0; nt < 12; ++nt) {
            short8 bf = *(const short8*)&w_s[(nt * 16 + col) * 40 + quad * 8];
            acc[0][nt] = MFMA(a0, bf, acc[0][nt]);
            acc[1][nt] = MFMA(a1, bf, acc[1][nt]);
        }
        if (s + 1 < 12) {
            #pragma unroll
            for (int i = 0; i < 4; ++i) xA[i] = xB[i];
            #pragma unroll
            for (int i = 0; i < 3; ++i) wA[i] = wB[i];
        }
    }

    // scatter accumulators -> q_s / k_s / vt_s (bf16)
    #pragma unroll
    for (int mi = 0; mi < 2; ++mi) {
        const int mt = wave * 2 + mi;
        #pragma unroll
        for (int nt = 0; nt < 12; ++nt) {
            #pragma unroll
            for (int r = 0; r < 4; ++r) {
                const int t = mt * 16 + quad * 4 + r;   // C/D: row = quad*4+reg
                const int n = nt * 16 + col;            // C/D: col = lane&15
                const unsigned short hv = f2bf(acc[mi][nt][r]);
                if (n < 64)       q_s[t * 72 + n] = hv;
                else if (n < 128) k_s[t * 72 + (n - 64)] = hv;
                else              vt_s[(n - 128) * 264 + t] = hv;
            }
        }
    }
    __syncthreads();

    // ---------------- Phase 2: causal flash attention ----------------
    // wave w owns query tiles {w, 15-w}: exactly 9 key-chunks of 32 per wave.
    const float scale = 0.125f;   // 1/sqrt(H)

    #pragma unroll
    for (int mi = 0; mi < 2; ++mi) {
        const int mt = mi ? (15 - wave) : wave;
        const int qoff = (mt * 16 + col) * 72 + quad * 8;
        const short8 aq0 = *(const short8*)&q_s[qoff];        // h 0..31
        const short8 aq1 = *(const short8*)&q_s[qoff + 32];   // h 32..63

        float m_i[4], l_i[4];
        v4f oacc[4];
        #pragma unroll
        for (int r = 0; r < 4; ++r) { m_i[r] = -INFINITY; l_i[r] = 0.f; }
        #pragma unroll
        for (int hn = 0; hn < 4; ++hn) oacc[hn] = (v4f){0.f, 0.f, 0.f, 0.f};

        unsigned short* Pb = x_s + wave * 16 * 40;   // wave-private 16x32 P buffer
        const int nch = mt / 2 + 1;

        for (int kc = 0; kc < nch; ++kc) {
            const int kb = kc * 32;
            v4f s0 = (v4f){0.f, 0.f, 0.f, 0.f};
            v4f s1 = (v4f){0.f, 0.f, 0.f, 0.f};
            {
                const int ko0 = (kb + col) * 72 + quad * 8;
                const int ko1 = (kb + 16 + col) * 72 + quad * 8;
                short8 b00 = *(const short8*)&k_s[ko0];
                short8 b01 = *(const short8*)&k_s[ko0 + 32];
                short8 b10 = *(const short8*)&k_s[ko1];
                short8 b11 = *(const short8*)&k_s[ko1 + 32];
                s0 = MFMA(aq0, b00, s0);
                s0 = MFMA(aq1, b01, s0);
                s1 = MFMA(aq0, b10, s1);
                s1 = MFMA(aq1, b11, s1);
            }
            const bool diag = (kc == mt / 2);   // wave-uniform
            #pragma unroll
            for (int r = 0; r < 4; ++r) {
                const int t = mt * 16 + quad * 4 + r;
                float v0 = s0[r] * scale;
                float v1 = s1[r] * scale;
                if (diag) {
                    if (kb + col > t)      v0 = -1e30f;
                    if (kb + 16 + col > t) v1 = -1e30f;
                }
                float cm = fmaxf(v0, v1);
                cm = fmaxf(cm, __shfl_xor(cm, 1));
                cm = fmaxf(cm, __shfl_xor(cm, 2));
                cm = fmaxf(cm, __shfl_xor(cm, 4));
                cm = fmaxf(cm, __shfl_xor(cm, 8));
                const float mo = m_i[r];
                const float mn = fmaxf(mo, cm);
                const float al = __expf(mo - mn);   // first chunk: exp(-inf)=0
                m_i[r] = mn;
                const float p0 = __expf(v0 - mn);
                const float p1 = __expf(v1 - mn);
                float rs = p0 + p1;
                rs += __shfl_xor(rs, 1);
                rs += __shfl_xor(rs, 2);
                rs += __shfl_xor(rs, 4);
                rs += __shfl_xor(rs, 8);
                l_i[r] = l_i[r] * al + rs;
                #pragma unroll
                for (int hn = 0; hn < 4; ++hn) oacc[hn][r] *= al;
                // P in C/D layout -> LDS (row = quad*4+r, col = key)
                Pb[(quad * 4 + r) * 40 + col]      = f2bf(p0);
                Pb[(quad * 4 + r) * 40 + 16 + col] = f2bf(p1);
            }
            __threadfence_block();   // order P writes before A-frag reads (same wave)
            // P re-read in A-operand layout: A[m=lane&15][k=quad*8+j]
            const short8 ap = *(const short8*)&Pb[col * 40 + quad * 8];
            #pragma unroll
            for (int hn = 0; hn < 4; ++hn) {
                short8 bv = *(const short8*)&vt_s[(hn * 16 + col) * 264 + kb + quad * 8];
                oacc[hn] = MFMA(ap, bv, oacc[hn]);
            }
        }

        // epilogue: normalize and store fp32
        #pragma unroll
        for (int r = 0; r < 4; ++r) {
            const int t = mt * 16 + quad * 4 + r;
            const float inv = 1.0f / l_i[r];
            float* op = out + ((size_t)b * TT + t) * HH;
            #pragma unroll
            for (int hn = 0; hn < 4; ++hn)
                op[hn * 16 + col] = oacc[hn][r] * inv;
        }
    }
}

extern "C" void kernel_launch(void* const* d_in, const int* in_sizes, int n_in,
                              void* d_out, int out_size, void* d_ws, size_t ws_size,
                              hipStream_t stream) {
    const float* x  = (const float*)d_in[0];
    const float* Wk = (const float*)d_in[1];
    const float* Wq = (const float*)d_in[2];
    const float* Wv = (const float*)d_in[3];
    float* out = (float*)d_out;

    // allow >64KB dynamic LDS (gfx950 has 160KiB/CU); idempotent, capture-safe
    (void)hipFuncSetAttribute((const void*)head_fused,
                              hipFuncAttributeMaxDynamicSharedMemorySize, SMEM_BYTES);

    head_fused<<<dim3(512), dim3(512), SMEM_BYTES, stream>>>(x, Wk, Wq, Wv, out);
}

// Round 2
// 348.113 us; speedup vs baseline: 1.0172x; 1.0172x over previous
//
#include <hip/hip_runtime.h>
#include <hip/hip_bf16.h>
#include <math.h>

// Problem constants: B=512, T=256, C=384, H=64
#define TT 256
#define CC 384
#define HH 64

typedef float v4f   __attribute__((ext_vector_type(4)));
typedef short short8 __attribute__((ext_vector_type(8)));

#define MFMA(a, b, c) __builtin_amdgcn_mfma_f32_16x16x32_bf16((a), (b), (c), 0, 0, 0)

__device__ __forceinline__ unsigned short f2bf(float f) {
    unsigned int u = __float_as_uint(f);
    u += 0x7FFFu + ((u >> 16) & 1u);   // round-to-nearest-even
    return (unsigned short)(u >> 16);
}

// ============================ Kernel 1: QKV projection =======================
// [131072 x 384] fp32  x  [384 x 192] (Wq|Wk|Wv rows, bf16-converted)
// -> q[bt][64], k[bt][64] bf16 ; v transposed vt[b][64][256] bf16
// 1024 blocks x 512 threads; each block owns 128 rows (never straddles a batch).
// LDS: staging x_s[128][40] + w_s[192][40]  (union with)
//      epilogue epi_qk[128][136] + epi_vt[64][136]   => 26112 ushort = 52.2 KB
__global__ __launch_bounds__(512, 4)
void qkv_proj(const float* __restrict__ x, const float* __restrict__ Wkp,
              const float* __restrict__ Wqp, const float* __restrict__ Wvp,
              unsigned short* __restrict__ qg, unsigned short* __restrict__ kg,
              unsigned short* __restrict__ vtg)
{
    __shared__ unsigned short sm[26112];
    unsigned short* x_s    = sm;           // [128][40]
    unsigned short* w_s    = sm + 5120;    // [192][40]  rows: 0-63 Wq, 64-127 Wk, 128-191 Wv
    unsigned short* epi_qk = sm;           // [128][136] cols: 0-63 q, 64-127 k
    unsigned short* epi_vt = sm + 17408;   // [64][136]

    const int tid  = threadIdx.x;
    const int wave = tid >> 6;
    const int lane = tid & 63;
    const int col  = lane & 15;
    const int quad = lane >> 4;
    const int row0 = blockIdx.x * 128;

    const int lr  = tid >> 3;         // 0..63
    const int lc4 = (tid & 7) * 4;    // float col within 32-wide K-step

    const float* xp  = x   + (size_t)(row0 + lr) * CC + lc4;   // rows lr, lr+64
    const float* wqp = Wqp + (size_t)lr * CC + lc4;
    const float* wkp = Wkp + (size_t)lr * CC + lc4;
    const float* wvp = Wvp + (size_t)lr * CC + lc4;

    v4f acc[12];
    #pragma unroll
    for (int j = 0; j < 12; ++j) acc[j] = (v4f){0.f, 0.f, 0.f, 0.f};

    // prefetch step 0
    float4 xA0 = *(const float4*)(xp);
    float4 xA1 = *(const float4*)(xp + 64 * CC);
    float4 wqA = *(const float4*)(wqp);
    float4 wkA = *(const float4*)(wkp);
    float4 wvA = *(const float4*)(wvp);

    const int afrag_off = (wave * 16 + col) * 40 + quad * 8;

    #pragma unroll
    for (int s = 0; s < 12; ++s) {
        float4 xB0, xB1, wqB, wkB, wvB;
        if (s < 11) {                       // next-step loads stay in flight across MFMA
            const int k0 = (s + 1) * 32;
            xB0 = *(const float4*)(xp + k0);
            xB1 = *(const float4*)(xp + 64 * CC + k0);
            wqB = *(const float4*)(wqp + k0);
            wkB = *(const float4*)(wkp + k0);
            wvB = *(const float4*)(wvp + k0);
        }
        __syncthreads();    // previous step's frag reads complete
        {
            ushort4 u;
            u.x = f2bf(xA0.x); u.y = f2bf(xA0.y); u.z = f2bf(xA0.z); u.w = f2bf(xA0.w);
            *(ushort4*)&x_s[lr * 40 + lc4] = u;
            u.x = f2bf(xA1.x); u.y = f2bf(xA1.y); u.z = f2bf(xA1.z); u.w = f2bf(xA1.w);
            *(ushort4*)&x_s[(lr + 64) * 40 + lc4] = u;
            u.x = f2bf(wqA.x); u.y = f2bf(wqA.y); u.z = f2bf(wqA.z); u.w = f2bf(wqA.w);
            *(ushort4*)&w_s[lr * 40 + lc4] = u;
            u.x = f2bf(wkA.x); u.y = f2bf(wkA.y); u.z = f2bf(wkA.z); u.w = f2bf(wkA.w);
            *(ushort4*)&w_s[(64 + lr) * 40 + lc4] = u;
            u.x = f2bf(wvA.x); u.y = f2bf(wvA.y); u.z = f2bf(wvA.z); u.w = f2bf(wvA.w);
            *(ushort4*)&w_s[(128 + lr) * 40 + lc4] = u;
        }
        __syncthreads();
        const short8 a = *(const short8*)&x_s[afrag_off];
        #pragma unroll
        for (int nt = 0; nt < 12; ++nt) {
            const short8 bf = *(const short8*)&w_s[(nt * 16 + col) * 40 + quad * 8];
            acc[nt] = MFMA(a, bf, acc[nt]);
        }
        if (s < 11) { xA0 = xB0; xA1 = xB1; wqA = wqB; wkA = wkB; wvA = wvB; }
    }

    // -------- epilogue: C/D frags -> LDS repack -> coalesced 16B global stores
    __syncthreads();
    #pragma unroll
    for (int nt = 0; nt < 12; ++nt) {
        #pragma unroll
        for (int r = 0; r < 4; ++r) {
            const int rl = wave * 16 + quad * 4 + r;   // C/D: row = quad*4+reg
            const int n  = nt * 16 + col;              // C/D: col = lane&15
            const unsigned short hv = f2bf(acc[nt][r]);
            if (nt < 8) epi_qk[rl * 136 + n] = hv;             // nt<8 <=> n<128, wave-uniform
            else        epi_vt[(n - 128) * 136 + rl] = hv;
        }
    }
    __syncthreads();

    const int b    = row0 >> 8;
    const int half = (row0 >> 7) & 1;

    #pragma unroll
    for (int p = 0; p < 4; ++p) {          // q/k: 128 rows x 16 chunks of 16B
        const int idx = tid + p * 512;
        const int r = idx >> 4, ch = idx & 15;
        const short8 v = *(const short8*)&epi_qk[r * 136 + ch * 8];
        const size_t base = (size_t)(row0 + r) * 64 + (ch & 7) * 8;
        if (ch < 8) *(short8*)&qg[base] = v;
        else        *(short8*)&kg[base] = v;
    }
    #pragma unroll
    for (int p = 0; p < 2; ++p) {          // vt: 64 h-rows x 16 chunks of 16B
        const int idx = tid + p * 512;
        const int h = idx >> 4, ch = idx & 15;
        const short8 v = *(const short8*)&epi_vt[h * 136 + ch * 8];
        *(short8*)&vtg[((size_t)b * 64 + h) * 256 + half * 128 + ch * 8] = v;
    }
}

// ============================ Kernel 2: causal flash attention ===============
// 1024 blocks (batch x q-half) x 256 threads (4 waves).
// Wave w owns q-tiles {qh*8+w, qh*8+7-w} (causal-balanced within the half).
// k / vt / q MFMA fragments loaded straight from global (L1/L2-resident per batch).
// LDS: only the per-wave 16x32 P round-trip buffer (C/D -> A-operand layout).
__global__ __launch_bounds__(256)
void attn(const unsigned short* __restrict__ qg, const unsigned short* __restrict__ kg,
          const unsigned short* __restrict__ vtg, float* __restrict__ out)
{
    __shared__ unsigned short Pb_all[4 * 16 * 40];
    const int tid  = threadIdx.x;
    const int wave = tid >> 6;
    const int lane = tid & 63;
    const int col  = lane & 15;
    const int quad = lane >> 4;
    const int b    = blockIdx.x >> 1;
    const int qh   = blockIdx.x & 1;

    unsigned short* Pb = Pb_all + wave * 640;
    const unsigned short* kb_base = kg  + (size_t)b * 256 * 64;
    const unsigned short* vt_base = vtg + (size_t)b * 64 * 256;
    const float scale = 0.125f;   // 1/sqrt(H)

    #pragma unroll
    for (int mi = 0; mi < 2; ++mi) {
        const int qt = qh * 8 + (mi ? (7 - wave) : wave);
        const size_t qoff = ((size_t)b * 256 + qt * 16 + col) * 64 + quad * 8;
        const short8 aq0 = *(const short8*)(qg + qoff);        // h 0..31
        const short8 aq1 = *(const short8*)(qg + qoff + 32);   // h 32..63

        float m_i[4], l_i[4];
        v4f oacc[4];
        #pragma unroll
        for (int r = 0; r < 4; ++r) { m_i[r] = -INFINITY; l_i[r] = 0.f; }
        #pragma unroll
        for (int hn = 0; hn < 4; ++hn) oacc[hn] = (v4f){0.f, 0.f, 0.f, 0.f};

        const int nch = qt / 2 + 1;
        for (int kc = 0; kc < nch; ++kc) {
            const int kb = kc * 32;
            v4f s0 = (v4f){0.f, 0.f, 0.f, 0.f};
            v4f s1 = (v4f){0.f, 0.f, 0.f, 0.f};
            {
                const int ko0 = (kb + col) * 64 + quad * 8;
                const int ko1 = (kb + 16 + col) * 64 + quad * 8;
                const short8 b00 = *(const short8*)(kb_base + ko0);
                const short8 b01 = *(const short8*)(kb_base + ko0 + 32);
                const short8 b10 = *(const short8*)(kb_base + ko1);
                const short8 b11 = *(const short8*)(kb_base + ko1 + 32);
                s0 = MFMA(aq0, b00, s0);
                s0 = MFMA(aq1, b01, s0);
                s1 = MFMA(aq0, b10, s1);
                s1 = MFMA(aq1, b11, s1);
            }
            const bool diag = (kc == qt / 2);   // wave-uniform
            #pragma unroll
            for (int r = 0; r < 4; ++r) {
                const int t = qt * 16 + quad * 4 + r;
                float v0 = s0[r] * scale;
                float v1 = s1[r] * scale;
                if (diag) {
                    if (kb + col > t)      v0 = -1e30f;
                    if (kb + 16 + col > t) v1 = -1e30f;
                }
                float cm = fmaxf(v0, v1);
                cm = fmaxf(cm, __shfl_xor(cm, 1));
                cm = fmaxf(cm, __shfl_xor(cm, 2));
                cm = fmaxf(cm, __shfl_xor(cm, 4));
                cm = fmaxf(cm, __shfl_xor(cm, 8));
                const float mo = m_i[r];
                const float mn = fmaxf(mo, cm);
                const float al = __expf(mo - mn);   // first chunk: exp(-inf)=0
                m_i[r] = mn;
                const float p0 = __expf(v0 - mn);
                const float p1 = __expf(v1 - mn);
                float rs = p0 + p1;
                rs += __shfl_xor(rs, 1);
                rs += __shfl_xor(rs, 2);
                rs += __shfl_xor(rs, 4);
                rs += __shfl_xor(rs, 8);
                l_i[r] = l_i[r] * al + rs;
                #pragma unroll
                for (int hn = 0; hn < 4; ++hn) oacc[hn][r] *= al;
                Pb[(quad * 4 + r) * 40 + col]      = f2bf(p0);
                Pb[(quad * 4 + r) * 40 + 16 + col] = f2bf(p1);
            }
            __threadfence_block();   // order wave-private P writes before A-frag read
            const short8 ap = *(const short8*)&Pb[col * 40 + quad * 8];
            #pragma unroll
            for (int hn = 0; hn < 4; ++hn) {
                const short8 bv = *(const short8*)(vt_base + (hn * 16 + col) * 256 + kb + quad * 8);
                oacc[hn] = MFMA(ap, bv, oacc[hn]);
            }
        }

        #pragma unroll
        for (int r = 0; r < 4; ++r) {
            const int t = qt * 16 + quad * 4 + r;
            const float inv = 1.0f / l_i[r];
            float* op = out + ((size_t)b * TT + t) * HH;
            #pragma unroll
            for (int hn = 0; hn < 4; ++hn)
                op[hn * 16 + col] = oacc[hn][r] * inv;
        }
    }
}

extern "C" void kernel_launch(void* const* d_in, const int* in_sizes, int n_in,
                              void* d_out, int out_size, void* d_ws, size_t ws_size,
                              hipStream_t stream) {
    const float* x  = (const float*)d_in[0];
    const float* Wk = (const float*)d_in[1];
    const float* Wq = (const float*)d_in[2];
    const float* Wv = (const float*)d_in[3];
    float* out = (float*)d_out;

    // workspace: q | k | vt  (bf16), 16 MB each
    unsigned short* qg  = (unsigned short*)d_ws;
    unsigned short* kg  = qg + (size_t)512 * 256 * 64;
    unsigned short* vtg = kg + (size_t)512 * 256 * 64;

    qkv_proj<<<dim3(1024), dim3(512), 0, stream>>>(x, Wk, Wq, Wv, qg, kg, vtg);
    attn<<<dim3(1024), dim3(256), 0, stream>>>(qg, kg, vtg, out);
}